// Round 1
// baseline (1382.119 us; speedup 1.0000x reference)
//
#include <hip/hip_runtime.h>

#define NODES 50000
#define EDGES 800000
#define GRAPHS 500
#define DIN 128
#define HID 512

// ---------------- graph structure build ----------------

__global__ void count_deg(const int* __restrict__ row, int* __restrict__ deg, int E) {
    int e = blockIdx.x * 256 + threadIdx.x;
    if (e < E) atomicAdd(&deg[row[e]], 1);
}

__global__ void compute_dinv(const int* __restrict__ deg, float* __restrict__ dinv, int N) {
    int n = blockIdx.x * 256 + threadIdx.x;
    if (n < N) dinv[n] = rsqrtf((float)(deg[n] + 1));  // +1 self loop; deg>=1 always
}

__global__ __launch_bounds__(1024) void scan_offsets(const int* __restrict__ deg,
                                                     int* __restrict__ off, int N) {
    __shared__ int sums[1024];
    int tid = threadIdx.x;
    int chunk = (N + 1023) / 1024;
    int start = tid * chunk;
    int end = min(start + chunk, N);
    int s = 0;
    for (int i = start; i < end; ++i) s += deg[i];
    sums[tid] = s;
    __syncthreads();
    for (int o = 1; o < 1024; o <<= 1) {
        int v = (tid >= o) ? sums[tid - o] : 0;
        __syncthreads();
        sums[tid] += v;
        __syncthreads();
    }
    int run = sums[tid] - s;  // exclusive prefix
    for (int i = start; i < end; ++i) { off[i] = run; run += deg[i]; }
    if (tid == 1023) off[N] = sums[1023];
}

__global__ void fill_csr(const int* __restrict__ row, const int* __restrict__ col,
                         const int* __restrict__ off, int* __restrict__ cursor,
                         int* __restrict__ csr_col, int E) {
    int e = blockIdx.x * 256 + threadIdx.x;
    if (e < E) {
        int r = row[e];
        int p = atomicAdd(&cursor[r], 1);
        csr_col[off[r] + p] = col[e];
    }
}

// ---------------- dense GEMM: C[M][512] = A[M][K] @ W[K][512] ----------------
// 8 rows per block; A-row loads are wave-uniform (scalar), W rows coalesced.

template <int ROWS>
__global__ __launch_bounds__(256) void gemm_rm(const float* __restrict__ A,
                                               const float* __restrict__ W,
                                               float* __restrict__ C, int K) {
    int j = blockIdx.x * 256 + threadIdx.x;          // output column [0,512)
    int n0 = blockIdx.y * ROWS;                       // first output row
    float acc[ROWS];
#pragma unroll
    for (int r = 0; r < ROWS; ++r) acc[r] = 0.f;
    const float* a = A + (long)n0 * K;
    const float* w = W + j;
#pragma unroll 8
    for (int k = 0; k < K; ++k) {
        float wv = w[(long)k * HID];
#pragma unroll
        for (int r = 0; r < ROWS; ++r) acc[r] += a[(long)r * K + k] * wv;
    }
#pragma unroll
    for (int r = 0; r < ROWS; ++r) C[((long)n0 + r) * HID + j] = acc[r];
}

// ---------------- GCN aggregation + bias + relu ----------------
// out[n] = relu( dinv[n] * ( sum_{c in N(n)} dinv[c]*H[c] + dinv[n]*H[n] ) + b )

__global__ __launch_bounds__(128) void gcn_agg(const float* __restrict__ H,
                                               const int* __restrict__ off,
                                               const int* __restrict__ csr_col,
                                               const float* __restrict__ dinv,
                                               const float* __restrict__ bias,
                                               float* __restrict__ out) {
    int n = blockIdx.x;
    int f = threadIdx.x * 4;                          // 128 threads x float4 = 512
    float dn = dinv[n];
    float4 acc = *(const float4*)&H[(long)n * HID + f];  // self loop
    acc.x *= dn; acc.y *= dn; acc.z *= dn; acc.w *= dn;
    int s = off[n], e = off[n + 1];
    for (int i = s; i < e; ++i) {
        int c = csr_col[i];
        float dc = dinv[c];
        float4 hv = *(const float4*)&H[(long)c * HID + f];
        acc.x += hv.x * dc; acc.y += hv.y * dc;
        acc.z += hv.z * dc; acc.w += hv.w * dc;
    }
    float4 b = *(const float4*)&bias[f];
    float4 o;
    o.x = fmaxf(acc.x * dn + b.x, 0.f);
    o.y = fmaxf(acc.y * dn + b.y, 0.f);
    o.z = fmaxf(acc.z * dn + b.z, 0.f);
    o.w = fmaxf(acc.w * dn + b.w, 0.f);
    *(float4*)&out[(long)n * HID + f] = o;
}

// ---------------- sum pooling per graph ----------------

__global__ void pool_kernel(const float* __restrict__ H, const int* __restrict__ ngi,
                            float* __restrict__ gh, int total) {
    int i = blockIdx.x * 256 + threadIdx.x;
    if (i < total) {
        int n = i >> 9;        // /512
        int f = i & 511;
        atomicAdd(&gh[(long)ngi[n] * HID + f], H[i]);
    }
}

// ---------------- classifier: logits[g] = gh[g] @ Wfc + bfc ----------------

__global__ __launch_bounds__(64) void logits_kernel(const float* __restrict__ gh,
                                                    const float* __restrict__ Wfc,
                                                    const float* __restrict__ bfc,
                                                    float* __restrict__ out) {
    int g = blockIdx.x;
    int t = threadIdx.x;
    float p0 = 0.f, p1 = 0.f;
    for (int k = t; k < HID; k += 64) {
        float h = gh[(long)g * HID + k];
        p0 += h * Wfc[k * 2 + 0];
        p1 += h * Wfc[k * 2 + 1];
    }
#pragma unroll
    for (int o = 32; o > 0; o >>= 1) {
        p0 += __shfl_down(p0, o);
        p1 += __shfl_down(p1, o);
    }
    if (t == 0) {
        out[g * 2 + 0] = p0 + bfc[0];
        out[g * 2 + 1] = p1 + bfc[1];
    }
}

// ---------------- launch ----------------

extern "C" void kernel_launch(void* const* d_in, const int* in_sizes, int n_in,
                              void* d_out, int out_size, void* d_ws, size_t ws_size,
                              hipStream_t stream) {
    const float* x   = (const float*)d_in[0];
    const int*   ei  = (const int*)d_in[1];
    const int*   ngi = (const int*)d_in[2];
    const float* W0  = (const float*)d_in[3];
    const float* b0  = (const float*)d_in[4];
    const float* W1  = (const float*)d_in[5];
    const float* b1  = (const float*)d_in[6];
    const float* Wfc = (const float*)d_in[7];
    const float* bfc = (const float*)d_in[8];
    float* out = (float*)d_out;

    const int* row = ei;           // edge_index[0]
    const int* col = ei + EDGES;   // edge_index[1]

    char* ws = (char*)d_ws;
    size_t o = 0;
    auto alloc = [&](size_t bytes) {
        o = (o + 255) & ~(size_t)255;
        void* p = ws + o;
        o += bytes;
        return p;
    };
    float* B0     = (float*)alloc((size_t)NODES * HID * 4);   // 102.4 MB
    float* B1     = (float*)alloc((size_t)NODES * HID * 4);   // 102.4 MB
    float* gh     = (float*)alloc((size_t)GRAPHS * HID * 4);  // 1 MB
    int*   deg    = (int*)alloc((size_t)NODES * 4);
    float* dinv   = (float*)alloc((size_t)NODES * 4);
    int*   off    = (int*)alloc((size_t)(NODES + 1) * 4);
    int*   cursor = (int*)alloc((size_t)NODES * 4);
    int*   csr    = (int*)alloc((size_t)EDGES * 4);

    hipMemsetAsync(deg, 0, (size_t)NODES * 4, stream);
    hipMemsetAsync(cursor, 0, (size_t)NODES * 4, stream);
    hipMemsetAsync(gh, 0, (size_t)GRAPHS * HID * 4, stream);

    count_deg<<<(EDGES + 255) / 256, 256, 0, stream>>>(row, deg, EDGES);
    compute_dinv<<<(NODES + 255) / 256, 256, 0, stream>>>(deg, dinv, NODES);
    scan_offsets<<<1, 1024, 0, stream>>>(deg, off, NODES);
    fill_csr<<<(EDGES + 255) / 256, 256, 0, stream>>>(row, col, off, cursor, csr, EDGES);

    // layer 0: B0 = x @ W0 ; B1 = relu(agg(B0) + b0)
    gemm_rm<8><<<dim3(HID / 256, NODES / 8), 256, 0, stream>>>(x, W0, B0, DIN);
    gcn_agg<<<NODES, 128, 0, stream>>>(B0, off, csr, dinv, b0, B1);

    // layer 1: B0 = B1 @ W1 ; B1 = relu(agg(B0) + b1)
    gemm_rm<8><<<dim3(HID / 256, NODES / 8), 256, 0, stream>>>(B1, W1, B0, HID);
    gcn_agg<<<NODES, 128, 0, stream>>>(B0, off, csr, dinv, b1, B1);

    // pooling + classifier
    int total = NODES * HID;
    pool_kernel<<<(total + 255) / 256, 256, 0, stream>>>(B1, ngi, gh, total);
    logits_kernel<<<GRAPHS, 64, 0, stream>>>(gh, Wfc, bfc, out);
}

// Round 2
// 566.657 us; speedup vs baseline: 2.4391x; 2.4391x over previous
//
#include <hip/hip_runtime.h>

#define NODES 50000
#define MP    50048          // NODES padded to multiple of 128
#define EDGES 800000
#define GRAPHS 500
#define DIN 128
#define HID 512

typedef short bf16x8 __attribute__((ext_vector_type(8)));
typedef float f32x4 __attribute__((ext_vector_type(4)));

__device__ inline float bl(unsigned u) { return __uint_as_float(u << 16); }
__device__ inline float bh(unsigned u) { return __uint_as_float(u & 0xffff0000u); }
__device__ inline unsigned short f2b(float f) {
    unsigned u = __float_as_uint(f);
    return (unsigned short)((u + 0x7fffu + ((u >> 16) & 1u)) >> 16);  // RNE
}

// ---------------- graph structure build ----------------

__global__ void count_deg(const int* __restrict__ row, int* __restrict__ deg, int E) {
    int e = blockIdx.x * 256 + threadIdx.x;
    if (e < E) atomicAdd(&deg[row[e]], 1);
}

__global__ void compute_dinv(const int* __restrict__ deg, float* __restrict__ dinv, int N) {
    int n = blockIdx.x * 256 + threadIdx.x;
    if (n < N) dinv[n] = rsqrtf((float)(deg[n] + 1));  // +1 self loop
}

__global__ __launch_bounds__(1024) void scan_offsets(const int* __restrict__ deg,
                                                     int* __restrict__ off, int N) {
    __shared__ int sums[1024];
    int tid = threadIdx.x;
    int chunk = (N + 1023) / 1024;
    int start = tid * chunk;
    int end = min(start + chunk, N);
    int s = 0;
    for (int i = start; i < end; ++i) s += deg[i];
    sums[tid] = s;
    __syncthreads();
    for (int o = 1; o < 1024; o <<= 1) {
        int v = (tid >= o) ? sums[tid - o] : 0;
        __syncthreads();
        sums[tid] += v;
        __syncthreads();
    }
    int run = sums[tid] - s;  // exclusive prefix
    for (int i = start; i < end; ++i) { off[i] = run; run += deg[i]; }
    if (tid == 1023) off[N] = sums[1023];
}

__global__ void fill_csr(const int* __restrict__ row, const int* __restrict__ col,
                         const int* __restrict__ off, int* __restrict__ cursor,
                         int* __restrict__ csr_col, int E) {
    int e = blockIdx.x * 256 + threadIdx.x;
    if (e < E) {
        int r = row[e];
        int p = atomicAdd(&cursor[r], 1);
        csr_col[off[r] + p] = col[e];
    }
}

// ---------------- graph pooling structure ----------------

__global__ void count_graph(const int* __restrict__ ngi, int* __restrict__ gcnt, int N) {
    int n = blockIdx.x * 256 + threadIdx.x;
    if (n < N) atomicAdd(&gcnt[ngi[n]], 1);
}

__global__ __launch_bounds__(512) void scan_graph(const int* __restrict__ gcnt,
                                                  int* __restrict__ goff) {
    __shared__ int s[512];
    int t = threadIdx.x;
    s[t] = (t < GRAPHS) ? gcnt[t] : 0;
    __syncthreads();
    for (int o = 1; o < 512; o <<= 1) {
        int v = (t >= o) ? s[t - o] : 0;
        __syncthreads();
        s[t] += v;
        __syncthreads();
    }
    if (t == 0) goff[0] = 0;
    if (t < GRAPHS) goff[t + 1] = s[t];
}

// ---------------- conversions ----------------

__global__ void cvt_x_bf16(const float* __restrict__ x, unsigned short* __restrict__ xb, int n4) {
    int i = blockIdx.x * 256 + threadIdx.x;
    if (i < n4) {
        float4 v = ((const float4*)x)[i];
        ushort4 o;
        o.x = f2b(v.x); o.y = f2b(v.y); o.z = f2b(v.z); o.w = f2b(v.w);
        ((ushort4*)xb)[i] = o;
    }
}

// W[K][512] -> WT[512][K] bf16
template <int K>
__global__ void transpose_w(const float* __restrict__ W, unsigned short* __restrict__ WT) {
    int n = blockIdx.x * 256 + threadIdx.x;  // column
    int k = blockIdx.y;
    if (n < HID) WT[(size_t)n * K + k] = f2b(W[(size_t)k * HID + n]);
}

// ---------------- bf16 MFMA GEMM: C[MP][512] = A[MP][K] @ W[K][512] ----------------
// 128x128 tile, BK=64, 4 waves; global_load_lds(16B) staging with XOR chunk
// swizzle (pre-swizzled source + swizzled ds_read -> conflict-free b128 reads).

template <int K>
__global__ __launch_bounds__(256) void gemm_mfma(const unsigned short* __restrict__ A,
                                                 const unsigned short* __restrict__ BT,
                                                 unsigned short* __restrict__ C) {
    __shared__ unsigned short As[128 * 64];
    __shared__ unsigned short Bs[128 * 64];
    const int t = threadIdx.x;
    const int w = t >> 6, l = t & 63;
    const int wr = w >> 1, wc = w & 1;
    const int m0 = blockIdx.y * 128;
    const int n0 = blockIdx.x * 128;
    f32x4 acc[4][4] = {};
    const int lr = l >> 3;                 // row within 8-row group
    const int swz = (l & 7) ^ lr;          // pre-swizzled source chunk

    for (int k0 = 0; k0 < K; k0 += 64) {
#pragma unroll
        for (int c = 0; c < 4; ++c) {
            const int rg = (w * 4 + c) * 8;  // tile-local row-group base
            const unsigned short* ga = &A[(size_t)(m0 + rg + lr) * K + k0 + swz * 8];
            const unsigned short* gb = &BT[(size_t)(n0 + rg + lr) * K + k0 + swz * 8];
            __builtin_amdgcn_global_load_lds(
                (const __attribute__((address_space(1))) void*)ga,
                (__attribute__((address_space(3))) void*)&As[rg * 64], 16, 0, 0);
            __builtin_amdgcn_global_load_lds(
                (const __attribute__((address_space(1))) void*)gb,
                (__attribute__((address_space(3))) void*)&Bs[rg * 64], 16, 0, 0);
        }
        __syncthreads();
#pragma unroll
        for (int kk = 0; kk < 2; ++kk) {
            const int ch = (kk * 4 + (l >> 4)) ^ (l & 7);  // swizzled read chunk
            bf16x8 af[4], bg[4];
#pragma unroll
            for (int m = 0; m < 4; ++m)
                af[m] = *(const bf16x8*)&As[(wr * 64 + m * 16 + (l & 15)) * 64 + ch * 8];
#pragma unroll
            for (int n = 0; n < 4; ++n)
                bg[n] = *(const bf16x8*)&Bs[(wc * 64 + n * 16 + (l & 15)) * 64 + ch * 8];
#pragma unroll
            for (int m = 0; m < 4; ++m)
#pragma unroll
                for (int n = 0; n < 4; ++n)
                    acc[m][n] = __builtin_amdgcn_mfma_f32_16x16x32_bf16(af[m], bg[n], acc[m][n], 0, 0, 0);
        }
        __syncthreads();
    }
    const int ro = 4 * (l >> 4);
    const int co = l & 15;
#pragma unroll
    for (int m = 0; m < 4; ++m)
#pragma unroll
        for (int n = 0; n < 4; ++n)
#pragma unroll
            for (int r = 0; r < 4; ++r) {
                int row = m0 + wr * 64 + m * 16 + ro + r;
                int col = n0 + wc * 64 + n * 16 + co;
                C[(size_t)row * HID + col] = f2b(acc[m][n][r]);
            }
}

// ---------------- GCN aggregation + bias + relu (bf16 in/out, fp32 accum) ----------------

__global__ __launch_bounds__(64) void gcn_agg_bf16(const unsigned short* __restrict__ H,
                                                   const int* __restrict__ off,
                                                   const int* __restrict__ csr_col,
                                                   const float* __restrict__ dinv,
                                                   const float* __restrict__ bias,
                                                   unsigned short* __restrict__ out) {
    int n = blockIdx.x, l = threadIdx.x;
    float dn = dinv[n];
    uint4 v = ((const uint4*)(H + (size_t)n * HID))[l];
    float a0 = bl(v.x) * dn, a1 = bh(v.x) * dn, a2 = bl(v.y) * dn, a3 = bh(v.y) * dn;
    float a4 = bl(v.z) * dn, a5 = bh(v.z) * dn, a6 = bl(v.w) * dn, a7 = bh(v.w) * dn;
    int s = off[n], e = off[n + 1];
    for (int i = s; i < e; ++i) {
        int c = csr_col[i];
        float dc = dinv[c];
        uint4 hv = ((const uint4*)(H + (size_t)c * HID))[l];
        a0 += bl(hv.x) * dc; a1 += bh(hv.x) * dc;
        a2 += bl(hv.y) * dc; a3 += bh(hv.y) * dc;
        a4 += bl(hv.z) * dc; a5 += bh(hv.z) * dc;
        a6 += bl(hv.w) * dc; a7 += bh(hv.w) * dc;
    }
    float4 b0 = ((const float4*)bias)[l * 2];
    float4 b1 = ((const float4*)bias)[l * 2 + 1];
    float o0 = fmaxf(a0 * dn + b0.x, 0.f), o1 = fmaxf(a1 * dn + b0.y, 0.f);
    float o2 = fmaxf(a2 * dn + b0.z, 0.f), o3 = fmaxf(a3 * dn + b0.w, 0.f);
    float o4 = fmaxf(a4 * dn + b1.x, 0.f), o5 = fmaxf(a5 * dn + b1.y, 0.f);
    float o6 = fmaxf(a6 * dn + b1.z, 0.f), o7 = fmaxf(a7 * dn + b1.w, 0.f);
    uint4 ov;
    ov.x = (unsigned)f2b(o0) | ((unsigned)f2b(o1) << 16);
    ov.y = (unsigned)f2b(o2) | ((unsigned)f2b(o3) << 16);
    ov.z = (unsigned)f2b(o4) | ((unsigned)f2b(o5) << 16);
    ov.w = (unsigned)f2b(o6) | ((unsigned)f2b(o7) << 16);
    ((uint4*)(out + (size_t)n * HID))[l] = ov;
}

// ---------------- sum pooling per graph (sorted ngi -> ranges) ----------------

__global__ __launch_bounds__(64) void pool_bf16(const unsigned short* __restrict__ H,
                                                const int* __restrict__ goff,
                                                float* __restrict__ gh) {
    int g = blockIdx.x, l = threadIdx.x;
    int s = goff[g], e = goff[g + 1];
    float a0 = 0, a1 = 0, a2 = 0, a3 = 0, a4 = 0, a5 = 0, a6 = 0, a7 = 0;
    for (int n = s; n < e; ++n) {
        uint4 v = ((const uint4*)(H + (size_t)n * HID))[l];
        a0 += bl(v.x); a1 += bh(v.x); a2 += bl(v.y); a3 += bh(v.y);
        a4 += bl(v.z); a5 += bh(v.z); a6 += bl(v.w); a7 += bh(v.w);
    }
    float4* o = (float4*)(gh + (size_t)g * HID);
    o[l * 2]     = make_float4(a0, a1, a2, a3);
    o[l * 2 + 1] = make_float4(a4, a5, a6, a7);
}

// ---------------- classifier ----------------

__global__ __launch_bounds__(64) void logits_kernel(const float* __restrict__ gh,
                                                    const float* __restrict__ Wfc,
                                                    const float* __restrict__ bfc,
                                                    float* __restrict__ out) {
    int g = blockIdx.x;
    int t = threadIdx.x;
    float p0 = 0.f, p1 = 0.f;
    for (int k = t; k < HID; k += 64) {
        float h = gh[(size_t)g * HID + k];
        p0 += h * Wfc[k * 2 + 0];
        p1 += h * Wfc[k * 2 + 1];
    }
#pragma unroll
    for (int o = 32; o > 0; o >>= 1) {
        p0 += __shfl_down(p0, o);
        p1 += __shfl_down(p1, o);
    }
    if (t == 0) {
        out[g * 2 + 0] = p0 + bfc[0];
        out[g * 2 + 1] = p1 + bfc[1];
    }
}

// ---------------- launch ----------------

extern "C" void kernel_launch(void* const* d_in, const int* in_sizes, int n_in,
                              void* d_out, int out_size, void* d_ws, size_t ws_size,
                              hipStream_t stream) {
    const float* x   = (const float*)d_in[0];
    const int*   ei  = (const int*)d_in[1];
    const int*   ngi = (const int*)d_in[2];
    const float* W0  = (const float*)d_in[3];
    const float* b0  = (const float*)d_in[4];
    const float* W1  = (const float*)d_in[5];
    const float* b1  = (const float*)d_in[6];
    const float* Wfc = (const float*)d_in[7];
    const float* bfc = (const float*)d_in[8];
    float* out = (float*)d_out;

    const int* row = ei;
    const int* col = ei + EDGES;

    char* ws = (char*)d_ws;
    size_t o = 0;
    auto alloc = [&](size_t bytes) {
        o = (o + 255) & ~(size_t)255;
        void* p = ws + o;
        o += bytes;
        return p;
    };
    unsigned short* XB  = (unsigned short*)alloc((size_t)MP * DIN * 2);   // 12.8 MB
    unsigned short* G   = (unsigned short*)alloc((size_t)MP * HID * 2);   // 51.25 MB
    unsigned short* H   = (unsigned short*)alloc((size_t)MP * HID * 2);   // 51.25 MB
    unsigned short* W0T = (unsigned short*)alloc((size_t)HID * DIN * 2);
    unsigned short* W1T = (unsigned short*)alloc((size_t)HID * HID * 2);
    float* gh    = (float*)alloc((size_t)GRAPHS * HID * 4);
    int*   deg   = (int*)alloc((size_t)NODES * 4);
    float* dinv  = (float*)alloc((size_t)NODES * 4);
    int*   off   = (int*)alloc((size_t)(NODES + 1) * 4);
    int*   cursor= (int*)alloc((size_t)NODES * 4);
    int*   csr   = (int*)alloc((size_t)EDGES * 4);
    int*   gcnt  = (int*)alloc(512 * 4);
    int*   goff  = (int*)alloc(512 * 4);

    hipMemsetAsync(deg, 0, (size_t)NODES * 4, stream);
    hipMemsetAsync(cursor, 0, (size_t)NODES * 4, stream);
    hipMemsetAsync(gcnt, 0, 512 * 4, stream);
    // pad rows must be finite for MFMA staging
    hipMemsetAsync(XB + (size_t)NODES * DIN, 0, (size_t)(MP - NODES) * DIN * 2, stream);
    hipMemsetAsync(H + (size_t)NODES * HID, 0, (size_t)(MP - NODES) * HID * 2, stream);

    count_deg<<<(EDGES + 255) / 256, 256, 0, stream>>>(row, deg, EDGES);
    compute_dinv<<<(NODES + 255) / 256, 256, 0, stream>>>(deg, dinv, NODES);
    scan_offsets<<<1, 1024, 0, stream>>>(deg, off, NODES);
    fill_csr<<<(EDGES + 255) / 256, 256, 0, stream>>>(row, col, off, cursor, csr, EDGES);
    count_graph<<<(NODES + 255) / 256, 256, 0, stream>>>(ngi, gcnt, NODES);
    scan_graph<<<1, 512, 0, stream>>>(gcnt, goff);

    cvt_x_bf16<<<((NODES * DIN / 4) + 255) / 256, 256, 0, stream>>>(x, XB, NODES * DIN / 4);
    transpose_w<DIN><<<dim3(2, DIN), 256, 0, stream>>>(W0, W0T);
    transpose_w<HID><<<dim3(2, HID), 256, 0, stream>>>(W1, W1T);

    // layer 0: G = XB @ W0 ; H = relu(agg(G) + b0)
    gemm_mfma<DIN><<<dim3(HID / 128, MP / 128), 256, 0, stream>>>(XB, W0T, G);
    gcn_agg_bf16<<<NODES, 64, 0, stream>>>(G, off, csr, dinv, b0, H);

    // layer 1: G = H @ W1 ; H = relu(agg(G) + b1)
    gemm_mfma<HID><<<dim3(HID / 128, MP / 128), 256, 0, stream>>>(H, W1T, G);
    gcn_agg_bf16<<<NODES, 64, 0, stream>>>(G, off, csr, dinv, b1, H);

    // pooling + classifier
    pool_bf16<<<GRAPHS, 64, 0, stream>>>(H, goff, gh);
    logits_kernel<<<GRAPHS, 64, 0, stream>>>(gh, Wfc, bfc, out);
}

// Round 3
// 482.544 us; speedup vs baseline: 2.8642x; 1.1743x over previous
//
#include <hip/hip_runtime.h>

#define NODES 50000
#define MP    50048          // NODES padded to multiple of 128
#define EDGES 800000
#define GRAPHS 500
#define DIN 128
#define HID 512

typedef short bf16x8 __attribute__((ext_vector_type(8)));
typedef float f32x4 __attribute__((ext_vector_type(4)));

__device__ inline float bl(unsigned u) { return __uint_as_float(u << 16); }
__device__ inline float bh(unsigned u) { return __uint_as_float(u & 0xffff0000u); }
__device__ inline unsigned short f2b(float f) {
    unsigned u = __float_as_uint(f);
    return (unsigned short)((u + 0x7fffu + ((u >> 16) & 1u)) >> 16);  // RNE
}

// ---------------- graph structure build ----------------

__global__ void count_deg(const int* __restrict__ row, int* __restrict__ deg, int E) {
    int e = blockIdx.x * 256 + threadIdx.x;
    if (e < E) atomicAdd(&deg[row[e]], 1);
}

__global__ void compute_dinv(const int* __restrict__ deg, float* __restrict__ dinv, int N) {
    int n = blockIdx.x * 256 + threadIdx.x;
    if (n < N) dinv[n] = rsqrtf((float)(deg[n] + 1));  // +1 self loop
}

__global__ __launch_bounds__(1024) void scan_offsets(const int* __restrict__ deg,
                                                     int* __restrict__ off, int N) {
    __shared__ int sums[1024];
    int tid = threadIdx.x;
    int chunk = (N + 1023) / 1024;
    int start = tid * chunk;
    int end = min(start + chunk, N);
    int s = 0;
    for (int i = start; i < end; ++i) s += deg[i];
    sums[tid] = s;
    __syncthreads();
    for (int o = 1; o < 1024; o <<= 1) {
        int v = (tid >= o) ? sums[tid - o] : 0;
        __syncthreads();
        sums[tid] += v;
        __syncthreads();
    }
    int run = sums[tid] - s;  // exclusive prefix
    for (int i = start; i < end; ++i) { off[i] = run; run += deg[i]; }
    if (tid == 1023) off[N] = sums[1023];
}

__global__ void fill_csr(const int* __restrict__ row, const int* __restrict__ col,
                         const int* __restrict__ off, int* __restrict__ cursor,
                         int* __restrict__ csr_col, int E) {
    int e = blockIdx.x * 256 + threadIdx.x;
    if (e < E) {
        int r = row[e];
        int p = atomicAdd(&cursor[r], 1);
        csr_col[off[r] + p] = col[e];
    }
}

// ---------------- graph pooling structure ----------------

__global__ void count_graph(const int* __restrict__ ngi, int* __restrict__ gcnt, int N) {
    int n = blockIdx.x * 256 + threadIdx.x;
    if (n < N) atomicAdd(&gcnt[ngi[n]], 1);
}

__global__ __launch_bounds__(512) void scan_graph(const int* __restrict__ gcnt,
                                                  int* __restrict__ goff) {
    __shared__ int s[512];
    int t = threadIdx.x;
    s[t] = (t < GRAPHS) ? gcnt[t] : 0;
    __syncthreads();
    for (int o = 1; o < 512; o <<= 1) {
        int v = (t >= o) ? s[t - o] : 0;
        __syncthreads();
        s[t] += v;
        __syncthreads();
    }
    if (t == 0) goff[0] = 0;
    if (t < GRAPHS) goff[t + 1] = s[t];
}

// ---------------- conversions ----------------

__global__ void cvt_x_bf16(const float* __restrict__ x, unsigned short* __restrict__ xb, int n4) {
    int i = blockIdx.x * 256 + threadIdx.x;
    if (i < n4) {
        float4 v = ((const float4*)x)[i];
        ushort4 o;
        o.x = f2b(v.x); o.y = f2b(v.y); o.z = f2b(v.z); o.w = f2b(v.w);
        ((ushort4*)xb)[i] = o;
    }
}

// W[K][512] -> WT[512][K] bf16
template <int K>
__global__ void transpose_w(const float* __restrict__ W, unsigned short* __restrict__ WT) {
    int n = blockIdx.x * 256 + threadIdx.x;  // column
    int k = blockIdx.y;
    if (n < HID) WT[(size_t)n * K + k] = f2b(W[(size_t)k * HID + n]);
}

// ---------------- layer-0 aggregation on 128-dim bf16 x (pure, pre-GEMM) ----------------
// wave per node, lane = 1 uint (2 feats); unroll-4 edge loop for MLP.

__global__ __launch_bounds__(256) void agg_x(const unsigned short* __restrict__ X,
                                             const int* __restrict__ off,
                                             const int* __restrict__ csr_col,
                                             const float* __restrict__ dinv,
                                             unsigned short* __restrict__ XA) {
    int n = blockIdx.x * 4 + (threadIdx.x >> 6);
    if (n >= NODES) return;
    int l = threadIdx.x & 63;
    const unsigned* X32 = (const unsigned*)X;
    float dn = dinv[n];
    unsigned sv = X32[(size_t)n * 64 + l];
    float a0 = bl(sv) * dn, a1 = bh(sv) * dn;
    int s = off[n], e = off[n + 1];
    int i = s;
    for (; i + 4 <= e; i += 4) {
        int c0 = csr_col[i], c1 = csr_col[i + 1], c2 = csr_col[i + 2], c3 = csr_col[i + 3];
        float d0 = dinv[c0], d1 = dinv[c1], d2 = dinv[c2], d3 = dinv[c3];
        unsigned v0 = X32[(size_t)c0 * 64 + l];
        unsigned v1 = X32[(size_t)c1 * 64 + l];
        unsigned v2 = X32[(size_t)c2 * 64 + l];
        unsigned v3 = X32[(size_t)c3 * 64 + l];
        a0 += bl(v0) * d0; a1 += bh(v0) * d0;
        a0 += bl(v1) * d1; a1 += bh(v1) * d1;
        a0 += bl(v2) * d2; a1 += bh(v2) * d2;
        a0 += bl(v3) * d3; a1 += bh(v3) * d3;
    }
    for (; i < e; ++i) {
        int c = csr_col[i];
        float dc = dinv[c];
        unsigned v = X32[(size_t)c * 64 + l];
        a0 += bl(v) * dc; a1 += bh(v) * dc;
    }
    a0 *= dn; a1 *= dn;
    ((unsigned*)XA)[(size_t)n * 64 + l] = (unsigned)f2b(a0) | ((unsigned)f2b(a1) << 16);
}

// ---------------- bf16 MFMA GEMM: C[MP][512] = A[MP][K] @ W[K][512] ----------------
// 128x128 tile, BK=64, 4 waves; global_load_lds(16B) staging with XOR chunk
// swizzle. Optional fused bias+relu epilogue.

template <int K, bool EPI>
__global__ __launch_bounds__(256) void gemm_mfma(const unsigned short* __restrict__ A,
                                                 const unsigned short* __restrict__ BT,
                                                 const float* __restrict__ bias,
                                                 unsigned short* __restrict__ C) {
    __shared__ unsigned short As[128 * 64];
    __shared__ unsigned short Bs[128 * 64];
    const int t = threadIdx.x;
    const int w = t >> 6, l = t & 63;
    const int wr = w >> 1, wc = w & 1;
    const int m0 = blockIdx.y * 128;
    const int n0 = blockIdx.x * 128;
    f32x4 acc[4][4] = {};
    const int lr = l >> 3;                 // row within 8-row group
    const int swz = (l & 7) ^ lr;          // pre-swizzled source chunk

    for (int k0 = 0; k0 < K; k0 += 64) {
#pragma unroll
        for (int c = 0; c < 4; ++c) {
            const int rg = (w * 4 + c) * 8;  // tile-local row-group base
            const unsigned short* ga = &A[(size_t)(m0 + rg + lr) * K + k0 + swz * 8];
            const unsigned short* gb = &BT[(size_t)(n0 + rg + lr) * K + k0 + swz * 8];
            __builtin_amdgcn_global_load_lds(
                (const __attribute__((address_space(1))) void*)ga,
                (__attribute__((address_space(3))) void*)&As[rg * 64], 16, 0, 0);
            __builtin_amdgcn_global_load_lds(
                (const __attribute__((address_space(1))) void*)gb,
                (__attribute__((address_space(3))) void*)&Bs[rg * 64], 16, 0, 0);
        }
        __syncthreads();
#pragma unroll
        for (int kk = 0; kk < 2; ++kk) {
            const int ch = (kk * 4 + (l >> 4)) ^ (l & 7);  // swizzled read chunk
            bf16x8 af[4], bg[4];
#pragma unroll
            for (int m = 0; m < 4; ++m)
                af[m] = *(const bf16x8*)&As[(wr * 64 + m * 16 + (l & 15)) * 64 + ch * 8];
#pragma unroll
            for (int n = 0; n < 4; ++n)
                bg[n] = *(const bf16x8*)&Bs[(wc * 64 + n * 16 + (l & 15)) * 64 + ch * 8];
#pragma unroll
            for (int m = 0; m < 4; ++m)
#pragma unroll
                for (int n = 0; n < 4; ++n)
                    acc[m][n] = __builtin_amdgcn_mfma_f32_16x16x32_bf16(af[m], bg[n], acc[m][n], 0, 0, 0);
        }
        __syncthreads();
    }
    const int ro = 4 * (l >> 4);
    const int co = l & 15;
#pragma unroll
    for (int m = 0; m < 4; ++m)
#pragma unroll
        for (int n = 0; n < 4; ++n) {
            int col = n0 + wc * 64 + n * 16 + co;
            float bv = EPI ? bias[col] : 0.f;
#pragma unroll
            for (int r = 0; r < 4; ++r) {
                int row = m0 + wr * 64 + m * 16 + ro + r;
                float v = acc[m][n][r];
                if (EPI) v = fmaxf(v + bv, 0.f);
                C[(size_t)row * HID + col] = f2b(v);
            }
        }
}

// ---------------- layer-1 aggregation (512-dim, unroll-4, fused bias+relu) ----------------

__global__ __launch_bounds__(64) void gcn_agg_bf16(const unsigned short* __restrict__ H,
                                                   const int* __restrict__ off,
                                                   const int* __restrict__ csr_col,
                                                   const float* __restrict__ dinv,
                                                   const float* __restrict__ bias,
                                                   unsigned short* __restrict__ out) {
    int n = blockIdx.x, l = threadIdx.x;
    const uint4* H4 = (const uint4*)H;
    float dn = dinv[n];
    uint4 v = H4[(size_t)n * 64 + l];
    float a0 = bl(v.x) * dn, a1 = bh(v.x) * dn, a2 = bl(v.y) * dn, a3 = bh(v.y) * dn;
    float a4 = bl(v.z) * dn, a5 = bh(v.z) * dn, a6 = bl(v.w) * dn, a7 = bh(v.w) * dn;
    int s = off[n], e = off[n + 1];
    int i = s;
    for (; i + 4 <= e; i += 4) {
        int c0 = csr_col[i], c1 = csr_col[i + 1], c2 = csr_col[i + 2], c3 = csr_col[i + 3];
        float d0 = dinv[c0], d1 = dinv[c1], d2 = dinv[c2], d3 = dinv[c3];
        uint4 v0 = H4[(size_t)c0 * 64 + l];
        uint4 v1 = H4[(size_t)c1 * 64 + l];
        uint4 v2 = H4[(size_t)c2 * 64 + l];
        uint4 v3 = H4[(size_t)c3 * 64 + l];
        a0 += bl(v0.x) * d0; a1 += bh(v0.x) * d0; a2 += bl(v0.y) * d0; a3 += bh(v0.y) * d0;
        a4 += bl(v0.z) * d0; a5 += bh(v0.z) * d0; a6 += bl(v0.w) * d0; a7 += bh(v0.w) * d0;
        a0 += bl(v1.x) * d1; a1 += bh(v1.x) * d1; a2 += bl(v1.y) * d1; a3 += bh(v1.y) * d1;
        a4 += bl(v1.z) * d1; a5 += bh(v1.z) * d1; a6 += bl(v1.w) * d1; a7 += bh(v1.w) * d1;
        a0 += bl(v2.x) * d2; a1 += bh(v2.x) * d2; a2 += bl(v2.y) * d2; a3 += bh(v2.y) * d2;
        a4 += bl(v2.z) * d2; a5 += bh(v2.z) * d2; a6 += bl(v2.w) * d2; a7 += bh(v2.w) * d2;
        a0 += bl(v3.x) * d3; a1 += bh(v3.x) * d3; a2 += bl(v3.y) * d3; a3 += bh(v3.y) * d3;
        a4 += bl(v3.z) * d3; a5 += bh(v3.z) * d3; a6 += bl(v3.w) * d3; a7 += bh(v3.w) * d3;
    }
    for (; i < e; ++i) {
        int c = csr_col[i];
        float dc = dinv[c];
        uint4 hv = H4[(size_t)c * 64 + l];
        a0 += bl(hv.x) * dc; a1 += bh(hv.x) * dc;
        a2 += bl(hv.y) * dc; a3 += bh(hv.y) * dc;
        a4 += bl(hv.z) * dc; a5 += bh(hv.z) * dc;
        a6 += bl(hv.w) * dc; a7 += bh(hv.w) * dc;
    }
    float4 b0 = ((const float4*)bias)[l * 2];
    float4 b1 = ((const float4*)bias)[l * 2 + 1];
    float o0 = fmaxf(a0 * dn + b0.x, 0.f), o1 = fmaxf(a1 * dn + b0.y, 0.f);
    float o2 = fmaxf(a2 * dn + b0.z, 0.f), o3 = fmaxf(a3 * dn + b0.w, 0.f);
    float o4 = fmaxf(a4 * dn + b1.x, 0.f), o5 = fmaxf(a5 * dn + b1.y, 0.f);
    float o6 = fmaxf(a6 * dn + b1.z, 0.f), o7 = fmaxf(a7 * dn + b1.w, 0.f);
    uint4 ov;
    ov.x = (unsigned)f2b(o0) | ((unsigned)f2b(o1) << 16);
    ov.y = (unsigned)f2b(o2) | ((unsigned)f2b(o3) << 16);
    ov.z = (unsigned)f2b(o4) | ((unsigned)f2b(o5) << 16);
    ov.w = (unsigned)f2b(o6) | ((unsigned)f2b(o7) << 16);
    ((uint4*)out)[(size_t)n * 64 + l] = ov;
}

// ---------------- sum pooling per graph (sorted ngi -> ranges) ----------------

__global__ __launch_bounds__(64) void pool_bf16(const unsigned short* __restrict__ H,
                                                const int* __restrict__ goff,
                                                float* __restrict__ gh) {
    int g = blockIdx.x, l = threadIdx.x;
    int s = goff[g], e = goff[g + 1];
    float a0 = 0, a1 = 0, a2 = 0, a3 = 0, a4 = 0, a5 = 0, a6 = 0, a7 = 0;
    for (int n = s; n < e; ++n) {
        uint4 v = ((const uint4*)H)[(size_t)n * 64 + l];
        a0 += bl(v.x); a1 += bh(v.x); a2 += bl(v.y); a3 += bh(v.y);
        a4 += bl(v.z); a5 += bh(v.z); a6 += bl(v.w); a7 += bh(v.w);
    }
    float4* o = (float4*)(gh + (size_t)g * HID);
    o[l * 2]     = make_float4(a0, a1, a2, a3);
    o[l * 2 + 1] = make_float4(a4, a5, a6, a7);
}

// ---------------- classifier ----------------

__global__ __launch_bounds__(64) void logits_kernel(const float* __restrict__ gh,
                                                    const float* __restrict__ Wfc,
                                                    const float* __restrict__ bfc,
                                                    float* __restrict__ out) {
    int g = blockIdx.x;
    int t = threadIdx.x;
    float p0 = 0.f, p1 = 0.f;
    for (int k = t; k < HID; k += 64) {
        float h = gh[(size_t)g * HID + k];
        p0 += h * Wfc[k * 2 + 0];
        p1 += h * Wfc[k * 2 + 1];
    }
#pragma unroll
    for (int o = 32; o > 0; o >>= 1) {
        p0 += __shfl_down(p0, o);
        p1 += __shfl_down(p1, o);
    }
    if (t == 0) {
        out[g * 2 + 0] = p0 + bfc[0];
        out[g * 2 + 1] = p1 + bfc[1];
    }
}

// ---------------- launch ----------------

extern "C" void kernel_launch(void* const* d_in, const int* in_sizes, int n_in,
                              void* d_out, int out_size, void* d_ws, size_t ws_size,
                              hipStream_t stream) {
    const float* x   = (const float*)d_in[0];
    const int*   ei  = (const int*)d_in[1];
    const int*   ngi = (const int*)d_in[2];
    const float* W0  = (const float*)d_in[3];
    const float* b0  = (const float*)d_in[4];
    const float* W1  = (const float*)d_in[5];
    const float* b1  = (const float*)d_in[6];
    const float* Wfc = (const float*)d_in[7];
    const float* bfc = (const float*)d_in[8];
    float* out = (float*)d_out;

    const int* row = ei;
    const int* col = ei + EDGES;

    char* ws = (char*)d_ws;
    size_t o = 0;
    auto alloc = [&](size_t bytes) {
        o = (o + 255) & ~(size_t)255;
        void* p = ws + o;
        o += bytes;
        return p;
    };
    unsigned short* XB  = (unsigned short*)alloc((size_t)NODES * DIN * 2);  // bf16 x
    unsigned short* XA  = (unsigned short*)alloc((size_t)MP * DIN * 2);     // agg(x)
    unsigned short* H   = (unsigned short*)alloc((size_t)MP * HID * 2);     // relu(XA@W0+b0), later reused for H2
    unsigned short* G   = (unsigned short*)alloc((size_t)MP * HID * 2);     // H@W1
    unsigned short* W0T = (unsigned short*)alloc((size_t)HID * DIN * 2);
    unsigned short* W1T = (unsigned short*)alloc((size_t)HID * HID * 2);
    float* gh    = (float*)alloc((size_t)GRAPHS * HID * 4);
    int*   deg   = (int*)alloc((size_t)NODES * 4);
    float* dinv  = (float*)alloc((size_t)NODES * 4);
    int*   off   = (int*)alloc((size_t)(NODES + 1) * 4);
    int*   cursor= (int*)alloc((size_t)NODES * 4);
    int*   csr   = (int*)alloc((size_t)EDGES * 4);
    int*   gcnt  = (int*)alloc(512 * 4);
    int*   goff  = (int*)alloc(512 * 4);

    hipMemsetAsync(deg, 0, (size_t)NODES * 4, stream);
    hipMemsetAsync(cursor, 0, (size_t)NODES * 4, stream);
    hipMemsetAsync(gcnt, 0, 512 * 4, stream);
    // pad rows of XA must be finite (GEMM0 reads all MP rows)
    hipMemsetAsync(XA + (size_t)NODES * DIN, 0, (size_t)(MP - NODES) * DIN * 2, stream);

    count_deg<<<(EDGES + 255) / 256, 256, 0, stream>>>(row, deg, EDGES);
    compute_dinv<<<(NODES + 255) / 256, 256, 0, stream>>>(deg, dinv, NODES);
    scan_offsets<<<1, 1024, 0, stream>>>(deg, off, NODES);
    fill_csr<<<(EDGES + 255) / 256, 256, 0, stream>>>(row, col, off, cursor, csr, EDGES);
    count_graph<<<(NODES + 255) / 256, 256, 0, stream>>>(ngi, gcnt, NODES);
    scan_graph<<<1, 512, 0, stream>>>(gcnt, goff);

    cvt_x_bf16<<<((NODES * DIN / 4) + 255) / 256, 256, 0, stream>>>(x, XB, NODES * DIN / 4);
    transpose_w<DIN><<<dim3(2, DIN), 256, 0, stream>>>(W0, W0T);
    transpose_w<HID><<<dim3(2, HID), 256, 0, stream>>>(W1, W1T);

    // layer 0 (reordered): XA = agg(XB); H = relu(XA @ W0 + b0)  [agg linear => commutes]
    agg_x<<<(NODES + 3) / 4, 256, 0, stream>>>(XB, off, csr, dinv, XA);
    gemm_mfma<DIN, true><<<dim3(HID / 128, MP / 128), 256, 0, stream>>>(XA, W0T, b0, H);

    // layer 1: G = H @ W1 ; H2(=H) = relu(agg(G) + b1)
    gemm_mfma<HID, false><<<dim3(HID / 128, MP / 128), 256, 0, stream>>>(H, W1T, nullptr, G);
    gcn_agg_bf16<<<NODES, 64, 0, stream>>>(G, off, csr, dinv, b1, H);

    // pooling + classifier
    pool_bf16<<<GRAPHS, 64, 0, stream>>>(H, goff, gh);
    logits_kernel<<<GRAPHS, 64, 0, stream>>>(gh, Wfc, bfc, out);
}